// Round 1
// baseline (1238.073 us; speedup 1.0000x reference)
//
#include <hip/hip_runtime.h>

// ---------------- setup kernels ----------------

__global__ __launch_bounds__(256) void deg_kernel(const int* __restrict__ src,
                                                  const int* __restrict__ dst,
                                                  int* __restrict__ out_deg,
                                                  int* __restrict__ in_deg, int E) {
  int e = blockIdx.x * 256 + threadIdx.x;
  if (e < E) {
    atomicAdd(&out_deg[src[e]], 1);
    atomicAdd(&in_deg[dst[e]], 1);
  }
}

__global__ __launch_bounds__(256) void norm_kernel(const int* __restrict__ out_deg,
                                                   const int* __restrict__ in_deg,
                                                   float* __restrict__ out_norm,
                                                   float* __restrict__ in_norm, int N) {
  int n = blockIdx.x * 256 + threadIdx.x;
  if (n < N) {
    out_norm[n] = 1.0f / sqrtf((float)max(out_deg[n], 1));
    in_norm[n]  = 1.0f / sqrtf((float)max(in_deg[n], 1));
  }
}

// single-block exclusive scan over N ints (N ~ 50k): wave shuffle scan + carry
__global__ __launch_bounds__(1024) void scan_kernel(const int* __restrict__ deg,
                                                    int* __restrict__ off, int n_) {
  __shared__ int wsum[16];
  __shared__ int carry_s;
  int tid = threadIdx.x;
  int lane = tid & 63;
  int wv = tid >> 6;
  if (tid == 0) carry_s = 0;
  __syncthreads();
  for (int base = 0; base < n_; base += 1024) {
    int i = base + tid;
    int v = (i < n_) ? deg[i] : 0;
    int x = v;
    for (int d = 1; d < 64; d <<= 1) {
      int y = __shfl_up(x, d, 64);
      if (lane >= d) x += y;
    }
    if (lane == 63) wsum[wv] = x;
    __syncthreads();
    if (wv == 0 && lane < 16) {
      int y = wsum[lane];
      int z = y;
      for (int d = 1; d < 16; d <<= 1) {
        int q = __shfl_up(z, d, 64);
        if (lane >= d) z += q;
      }
      wsum[lane] = z - y;  // exclusive across waves
    }
    __syncthreads();
    int wpre = wsum[wv];
    int c = carry_s;
    if (i < n_) off[i] = c + wpre + (x - v);
    __syncthreads();
    if (tid == 1023) carry_s = c + wpre + x;
    __syncthreads();
  }
  if (tid == 0) off[n_] = carry_s;
}

__global__ __launch_bounds__(256) void scatter_kernel(const int* __restrict__ src,
                                                      const int* __restrict__ dst,
                                                      const int* __restrict__ in_off,
                                                      int* __restrict__ cursor,
                                                      int* __restrict__ csr_src, int E) {
  int e = blockIdx.x * 256 + threadIdx.x;
  if (e < E) {
    int d = dst[e];
    int p = atomicAdd(&cursor[d], 1);
    csr_src[in_off[d] + p] = src[e];
  }
}

// ---------------- graph-conv layer ----------------
// One wave per node. Gather h[src]*out_norm[src] (float4 slices), scale by
// in_norm[dst] into per-wave LDS, then per-node matmul + bias (+relu).
// IT_LAYOUT=true: input node block is [f][t] (raw temporal_features);
// otherwise [t][f] with LDS row stride RS (padded to break bank conflicts).
template <int F_IN, int F_OUT, int RS, bool IT_LAYOUT, bool RELU>
__global__ __launch_bounds__(256) void layer_kernel(
    const float* __restrict__ h_in, const int* __restrict__ csr_src,
    const int* __restrict__ in_off, const float* __restrict__ out_norm,
    const float* __restrict__ in_norm, const float* __restrict__ W,
    const float* __restrict__ bias, float* __restrict__ h_out, int N) {
  constexpr int FT_IN = F_IN * 8;
  constexpr int NF4 = FT_IN / 4;  // 64 / 80 / 128
  constexpr int AGG = IT_LAYOUT ? FT_IN : RS * 8;
  __shared__ float agg_all[4][AGG];
  int lane = threadIdx.x & 63;
  int wave = threadIdx.x >> 6;
  float* agg = agg_all[wave];
  int n = blockIdx.x * 4 + wave;
  bool valid = (n < N);

  if (valid) {
    int e0 = in_off[n], e1 = in_off[n + 1];
    const float4* h4 = (const float4*)h_in;
    float4 a0 = make_float4(0.f, 0.f, 0.f, 0.f);
    float4 a1 = make_float4(0.f, 0.f, 0.f, 0.f);
    for (int j = e0; j < e1; ++j) {
      int s = csr_src[j];
      float ws = out_norm[s];
      const float4* p = h4 + (size_t)s * NF4;
      float4 v = p[lane];
      a0.x += v.x * ws; a0.y += v.y * ws; a0.z += v.z * ws; a0.w += v.w * ws;
      if constexpr (NF4 > 64) {
        if (NF4 >= 128 || lane < NF4 - 64) {
          float4 u = p[64 + lane];
          a1.x += u.x * ws; a1.y += u.y * ws; a1.z += u.z * ws; a1.w += u.w * ws;
        }
      }
    }
    float innm = in_norm[n];
    a0.x *= innm; a0.y *= innm; a0.z *= innm; a0.w *= innm;
    a1.x *= innm; a1.y *= innm; a1.z *= innm; a1.w *= innm;
    // store to LDS (linear element el -> layout address)
    {
      int el = lane * 4;
      float* dst0;
      if constexpr (IT_LAYOUT) dst0 = &agg[el];
      else { int t = el / F_IN; int i = el - t * F_IN; dst0 = &agg[t * RS + i]; }
      *(float4*)dst0 = a0;
      if constexpr (NF4 > 64) {
        if (NF4 >= 128 || lane < NF4 - 64) {
          int el1 = (64 + lane) * 4;
          float* dst1;
          if constexpr (IT_LAYOUT) dst1 = &agg[el1];
          else { int t = el1 / F_IN; int i = el1 - t * F_IN; dst1 = &agg[t * RS + i]; }
          *(float4*)dst1 = a1;
        }
      }
    }
  }
  __syncthreads();

  if (valid) {
    constexpr int G = F_OUT / 8;  // 5 or 8
    int t = lane >> 3, og = lane & 7;
    float acc[G];
    if constexpr (G == 8) {
      float4 bA = *(const float4*)&bias[og * 8];
      float4 bB = *(const float4*)&bias[og * 8 + 4];
      acc[0] = bA.x; acc[1] = bA.y; acc[2] = bA.z; acc[3] = bA.w;
      acc[4] = bB.x; acc[5] = bB.y; acc[6] = bB.z; acc[7] = bB.w;
    } else {
#pragma unroll
      for (int c = 0; c < G; ++c) acc[c] = bias[og * G + c];
    }
#pragma unroll 4
    for (int i = 0; i < F_IN; ++i) {
      float a;
      if constexpr (IT_LAYOUT) a = agg[i * 8 + t];
      else a = agg[t * RS + i];
      if constexpr (G == 8) {
        float4 wA = *(const float4*)&W[i * F_OUT + og * 8];
        float4 wB = *(const float4*)&W[i * F_OUT + og * 8 + 4];
        acc[0] += a * wA.x; acc[1] += a * wA.y; acc[2] += a * wA.z; acc[3] += a * wA.w;
        acc[4] += a * wB.x; acc[5] += a * wB.y; acc[6] += a * wB.z; acc[7] += a * wB.w;
      } else {
#pragma unroll
        for (int c = 0; c < G; ++c) acc[c] += a * W[i * F_OUT + og * G + c];
      }
    }
    float* orow = h_out + (size_t)n * (F_OUT * 8) + t * F_OUT + og * G;
    if constexpr (G == 8) {
      float4 r0, r1;
      if constexpr (RELU) {
        r0 = make_float4(fmaxf(acc[0], 0.f), fmaxf(acc[1], 0.f), fmaxf(acc[2], 0.f), fmaxf(acc[3], 0.f));
        r1 = make_float4(fmaxf(acc[4], 0.f), fmaxf(acc[5], 0.f), fmaxf(acc[6], 0.f), fmaxf(acc[7], 0.f));
      } else {
        r0 = make_float4(acc[0], acc[1], acc[2], acc[3]);
        r1 = make_float4(acc[4], acc[5], acc[6], acc[7]);
      }
      *(float4*)&orow[0] = r0;
      *(float4*)&orow[4] = r1;
    } else {
#pragma unroll
      for (int c = 0; c < G; ++c) {
        float v = acc[c];
        if constexpr (RELU) v = fmaxf(v, 0.f);
        orow[c] = v;
      }
    }
  }
}

// ---------------- temporal conv1d (k=3, pad=1) ----------------
// h3 (= d_out, aliasing safe: per-node read->LDS->sync->write) layout [n][t][i];
// out layout [n][o][t]. Wc staged transposed in LDS; one wave per node.
#define CONV_NPW 8
__global__ __launch_bounds__(256) void conv_kernel(const float* h3, const float* __restrict__ Wc,
                                                   const float* __restrict__ bc, float* out, int N) {
  __shared__ float wc_t[192 * 64];      // [(i*3+k)*64 + o], 48 KB
  __shared__ float h3t[4][64 * 12];     // per-wave, [i*12 + t] (pad -> b128-friendly)
  int tid = threadIdx.x, lane = tid & 63, wave = tid >> 6;

  for (int m4 = tid; m4 < 3072; m4 += 256) {  // 12288 floats as float4
    float4 v = ((const float4*)Wc)[m4];
    int m = m4 * 4;
    int o = m / 192, q = m % 192;  // q = i*3+k; float4 never crosses an o row
    wc_t[(q + 0) * 64 + o] = v.x;
    wc_t[(q + 1) * 64 + o] = v.y;
    wc_t[(q + 2) * 64 + o] = v.z;
    wc_t[(q + 3) * 64 + o] = v.w;
  }
  __syncthreads();
  float bo = bc[lane];
  float* ht = h3t[wave];

  for (int it = 0; it < CONV_NPW; ++it) {
    int n = blockIdx.x * (4 * CONV_NPW) + it * 4 + wave;
    bool valid = (n < N);
    if (valid) {
      const float* srcp = &h3[(size_t)n * 512];
#pragma unroll
      for (int r = 0; r < 8; ++r) ht[lane * 12 + r] = srcp[r * 64 + lane];  // transpose
    }
    __syncthreads();
    if (valid) {
      float acc[8];
#pragma unroll
      for (int t = 0; t < 8; ++t) acc[t] = bo;
#pragma unroll 4
      for (int i = 0; i < 64; ++i) {
        float4 hA = *(const float4*)&ht[i * 12];
        float4 hB = *(const float4*)&ht[i * 12 + 4];
        float w0 = wc_t[(i * 3 + 0) * 64 + lane];
        float w1 = wc_t[(i * 3 + 1) * 64 + lane];
        float w2 = wc_t[(i * 3 + 2) * 64 + lane];
        float h[8] = {hA.x, hA.y, hA.z, hA.w, hB.x, hB.y, hB.z, hB.w};
#pragma unroll
        for (int t = 0; t < 8; ++t) acc[t] += w1 * h[t];
#pragma unroll
        for (int t = 1; t < 8; ++t) acc[t] += w0 * h[t - 1];
#pragma unroll
        for (int t = 0; t < 7; ++t) acc[t] += w2 * h[t + 1];
      }
      float4 r0 = make_float4(acc[0], acc[1], acc[2], acc[3]);
      float4 r1 = make_float4(acc[4], acc[5], acc[6], acc[7]);
      float4* dst = (float4*)&out[(size_t)n * 512 + lane * 8];
      dst[0] = r0;
      dst[1] = r1;
    }
    __syncthreads();
  }
}

// ---------------- launch ----------------

extern "C" void kernel_launch(void* const* d_in, const int* in_sizes, int n_in,
                              void* d_out, int out_size, void* d_ws, size_t ws_size,
                              hipStream_t stream) {
  const float* tf = (const float*)d_in[0];
  const int* src = (const int*)d_in[1];
  const int* dst = (const int*)d_in[2];
  const float* W1 = (const float*)d_in[3];
  const float* b1 = (const float*)d_in[4];
  const float* W2 = (const float*)d_in[5];
  const float* b2 = (const float*)d_in[6];
  const float* W3 = (const float*)d_in[7];
  const float* b3 = (const float*)d_in[8];
  const float* Wc = (const float*)d_in[9];
  const float* bc = (const float*)d_in[10];

  int N = in_sizes[0] / 256;  // [N, 32, 8]
  int E = in_sizes[1];

  char* ws = (char*)d_ws;
  size_t pos = 0;
  auto alloc = [&](size_t bytes) -> void* {
    void* p = ws + pos;
    pos += (bytes + 255) & ~(size_t)255;
    return p;
  };
  int* in_deg   = (int*)alloc((size_t)N * 4);
  int* out_deg  = (int*)alloc((size_t)N * 4);
  int* cursor   = (int*)alloc((size_t)N * 4);
  int* in_off   = (int*)alloc((size_t)(N + 1) * 4);
  float* o_norm = (float*)alloc((size_t)N * 4);
  float* i_norm = (float*)alloc((size_t)N * 4);
  int* csr      = (int*)alloc((size_t)E * 4);
  float* h1     = (float*)alloc((size_t)N * 320 * 4);
  float* h2     = (float*)alloc((size_t)N * 512 * 4);
  float* h3     = (float*)d_out;  // reuse d_out as h3 storage (conv is node-local)

  // zero the three atomic counter arrays (contiguous region)
  hipMemsetAsync(in_deg, 0, (size_t)((char*)in_off - (char*)in_deg), stream);

  deg_kernel<<<(E + 255) / 256, 256, 0, stream>>>(src, dst, out_deg, in_deg, E);
  norm_kernel<<<(N + 255) / 256, 256, 0, stream>>>(out_deg, in_deg, o_norm, i_norm, N);
  scan_kernel<<<1, 1024, 0, stream>>>(in_deg, in_off, N);
  scatter_kernel<<<(E + 255) / 256, 256, 0, stream>>>(src, dst, in_off, cursor, csr, E);

  int lg = (N + 3) / 4;
  layer_kernel<32, 40, 0, true, true><<<lg, 256, 0, stream>>>(
      tf, csr, in_off, o_norm, i_norm, W1, b1, h1, N);
  layer_kernel<40, 64, 40, false, true><<<lg, 256, 0, stream>>>(
      h1, csr, in_off, o_norm, i_norm, W2, b2, h2, N);
  layer_kernel<64, 64, 72, false, false><<<lg, 256, 0, stream>>>(
      h2, csr, in_off, o_norm, i_norm, W3, b3, h3, N);

  conv_kernel<<<(N + 4 * CONV_NPW - 1) / (4 * CONV_NPW), 256, 0, stream>>>(
      h3, Wc, bc, (float*)d_out, N);
}

// Round 2
// 1090.184 us; speedup vs baseline: 1.1357x; 1.1357x over previous
//
#include <hip/hip_runtime.h>

// ---------------- setup kernels ----------------

__global__ __launch_bounds__(256) void deg_kernel(const int* __restrict__ src,
                                                  const int* __restrict__ dst,
                                                  int* __restrict__ out_deg,
                                                  int* __restrict__ in_deg, int E) {
  int e = blockIdx.x * 256 + threadIdx.x;
  if (e < E) {
    atomicAdd(&out_deg[src[e]], 1);
    atomicAdd(&in_deg[dst[e]], 1);
  }
}

__global__ __launch_bounds__(256) void norm_kernel(const int* __restrict__ out_deg,
                                                   const int* __restrict__ in_deg,
                                                   float* __restrict__ out_norm,
                                                   float* __restrict__ in_norm, int N) {
  int n = blockIdx.x * 256 + threadIdx.x;
  if (n < N) {
    out_norm[n] = 1.0f / sqrtf((float)max(out_deg[n], 1));
    in_norm[n]  = 1.0f / sqrtf((float)max(in_deg[n], 1));
  }
}

// ---- parallel exclusive scan over N ints: partial sums -> scan partials -> apply ----
// CHUNK = 1024 elements per block.

__global__ __launch_bounds__(256) void scan_partial_kernel(const int* __restrict__ deg,
                                                           int* __restrict__ partial, int N) {
  __shared__ int ws[4];
  int tid = threadIdx.x, lane = tid & 63, wv = tid >> 6;
  int base = blockIdx.x * 1024;
  int v = 0;
#pragma unroll
  for (int k = 0; k < 4; ++k) {
    int i = base + tid + k * 256;
    if (i < N) v += deg[i];
  }
  for (int d = 32; d > 0; d >>= 1) v += __shfl_down(v, d, 64);
  if (lane == 0) ws[wv] = v;
  __syncthreads();
  if (tid == 0) partial[blockIdx.x] = ws[0] + ws[1] + ws[2] + ws[3];
}

__global__ __launch_bounds__(1024) void scan_partials_kernel(int* __restrict__ partial, int P) {
  __shared__ int wsum[16];
  int tid = threadIdx.x, lane = tid & 63, wv = tid >> 6;
  int v = (tid < P) ? partial[tid] : 0;
  int x = v;
  for (int d = 1; d < 64; d <<= 1) {
    int y = __shfl_up(x, d, 64);
    if (lane >= d) x += y;
  }
  if (lane == 63) wsum[wv] = x;
  __syncthreads();
  if (wv == 0 && lane < 16) {
    int y = wsum[lane];
    int z = y;
    for (int d = 1; d < 16; d <<= 1) {
      int q = __shfl_up(z, d, 64);
      if (lane >= d) z += q;
    }
    wsum[lane] = z - y;
  }
  __syncthreads();
  if (tid < P) partial[tid] = wsum[wv] + x - v;  // exclusive
}

__global__ __launch_bounds__(1024) void scan_apply_kernel(const int* __restrict__ deg,
                                                          const int* __restrict__ partial,
                                                          int* __restrict__ off, int N) {
  __shared__ int wsum[16];
  int tid = threadIdx.x, lane = tid & 63, wv = tid >> 6;
  int i = blockIdx.x * 1024 + tid;
  int v = (i < N) ? deg[i] : 0;
  int x = v;
  for (int d = 1; d < 64; d <<= 1) {
    int y = __shfl_up(x, d, 64);
    if (lane >= d) x += y;
  }
  if (lane == 63) wsum[wv] = x;
  __syncthreads();
  if (wv == 0 && lane < 16) {
    int y = wsum[lane];
    int z = y;
    for (int d = 1; d < 16; d <<= 1) {
      int q = __shfl_up(z, d, 64);
      if (lane >= d) z += q;
    }
    wsum[lane] = z - y;
  }
  __syncthreads();
  int excl = partial[blockIdx.x] + wsum[wv] + (x - v);
  if (i < N) off[i] = excl;
  if (i == N - 1) off[N] = excl + v;
}

__global__ __launch_bounds__(256) void scatter_kernel(const int* __restrict__ src,
                                                      const int* __restrict__ dst,
                                                      const int* __restrict__ in_off,
                                                      int* __restrict__ cursor,
                                                      int* __restrict__ csr_src, int E) {
  int e = blockIdx.x * 256 + threadIdx.x;
  if (e < E) {
    int d = dst[e];
    int p = atomicAdd(&cursor[d], 1);
    csr_src[in_off[d] + p] = src[e];
  }
}

// ---------------- graph-conv layer ----------------
// One wave per node. Gather h[src] (float4 slices, 4x edge-unrolled for MLP),
// scale by in_norm[dst] into per-wave LDS, then per-node matmul + bias (+relu).
// GNORM: gather multiplies by out_norm[s] per edge (layer 1 only; layers 2/3
// consume producer-prescaled inputs). SCALE_OUT: epilogue multiplies the
// output by out_norm[n] so the NEXT layer's gather can skip the norm load.
// IT_LAYOUT=true: input node block is [f][t] (raw temporal_features);
// otherwise [t][f] with LDS row stride RS (padded to break bank conflicts).
template <int F_IN, int F_OUT, int RS, bool IT_LAYOUT, bool RELU, bool GNORM, bool SCALE_OUT>
__global__ __launch_bounds__(256) void layer_kernel(
    const float* __restrict__ h_in, const int* __restrict__ csr_src,
    const int* __restrict__ in_off, const float* __restrict__ out_norm,
    const float* __restrict__ in_norm, const float* __restrict__ W,
    const float* __restrict__ bias, float* __restrict__ h_out, int N) {
  constexpr int FT_IN = F_IN * 8;
  constexpr int NF4 = FT_IN / 4;  // 64 / 80 / 128
  constexpr int AGG = IT_LAYOUT ? FT_IN : RS * 8;
  __shared__ float agg_all[4][AGG];
  int lane = threadIdx.x & 63;
  int wave = threadIdx.x >> 6;
  float* agg = agg_all[wave];
  int n = blockIdx.x * 4 + wave;
  bool valid = (n < N);

  if (valid) {
    int e0 = in_off[n], e1 = in_off[n + 1];
    const float4* h4 = (const float4*)h_in;
    float4 a0 = make_float4(0.f, 0.f, 0.f, 0.f);
    float4 c0 = make_float4(0.f, 0.f, 0.f, 0.f);
    float4 a1 = make_float4(0.f, 0.f, 0.f, 0.f);
    float4 c1 = make_float4(0.f, 0.f, 0.f, 0.f);
    const bool hi = (NF4 >= 128) || (lane < NF4 - 64);  // second-slice predicate
    int j = e0;
    for (; j + 4 <= e1; j += 4) {
      int s0 = csr_src[j], s1 = csr_src[j + 1], s2 = csr_src[j + 2], s3 = csr_src[j + 3];
      const float4* p0 = h4 + (size_t)s0 * NF4;
      const float4* p1 = h4 + (size_t)s1 * NF4;
      const float4* p2 = h4 + (size_t)s2 * NF4;
      const float4* p3 = h4 + (size_t)s3 * NF4;
      float w0 = 1.f, w1 = 1.f, w2 = 1.f, w3 = 1.f;
      if constexpr (GNORM) {
        w0 = out_norm[s0]; w1 = out_norm[s1]; w2 = out_norm[s2]; w3 = out_norm[s3];
      }
      float4 v0 = p0[lane], v1 = p1[lane], v2 = p2[lane], v3 = p3[lane];
      float4 u0, u1, u2, u3;
      if constexpr (NF4 > 64) {
        if (hi) { u0 = p0[64 + lane]; u1 = p1[64 + lane]; u2 = p2[64 + lane]; u3 = p3[64 + lane]; }
      }
      if constexpr (GNORM) {
        a0.x += v0.x * w0; a0.y += v0.y * w0; a0.z += v0.z * w0; a0.w += v0.w * w0;
        c0.x += v1.x * w1; c0.y += v1.y * w1; c0.z += v1.z * w1; c0.w += v1.w * w1;
        a0.x += v2.x * w2; a0.y += v2.y * w2; a0.z += v2.z * w2; a0.w += v2.w * w2;
        c0.x += v3.x * w3; c0.y += v3.y * w3; c0.z += v3.z * w3; c0.w += v3.w * w3;
      } else {
        a0.x += v0.x; a0.y += v0.y; a0.z += v0.z; a0.w += v0.w;
        c0.x += v1.x; c0.y += v1.y; c0.z += v1.z; c0.w += v1.w;
        a0.x += v2.x; a0.y += v2.y; a0.z += v2.z; a0.w += v2.w;
        c0.x += v3.x; c0.y += v3.y; c0.z += v3.z; c0.w += v3.w;
      }
      if constexpr (NF4 > 64) {
        if (hi) {
          if constexpr (GNORM) {
            a1.x += u0.x * w0; a1.y += u0.y * w0; a1.z += u0.z * w0; a1.w += u0.w * w0;
            c1.x += u1.x * w1; c1.y += u1.y * w1; c1.z += u1.z * w1; c1.w += u1.w * w1;
            a1.x += u2.x * w2; a1.y += u2.y * w2; a1.z += u2.z * w2; a1.w += u2.w * w2;
            c1.x += u3.x * w3; c1.y += u3.y * w3; c1.z += u3.z * w3; c1.w += u3.w * w3;
          } else {
            a1.x += u0.x; a1.y += u0.y; a1.z += u0.z; a1.w += u0.w;
            c1.x += u1.x; c1.y += u1.y; c1.z += u1.z; c1.w += u1.w;
            a1.x += u2.x; a1.y += u2.y; a1.z += u2.z; a1.w += u2.w;
            c1.x += u3.x; c1.y += u3.y; c1.z += u3.z; c1.w += u3.w;
          }
        }
      }
    }
    for (; j < e1; ++j) {
      int s = csr_src[j];
      float ws = 1.f;
      if constexpr (GNORM) ws = out_norm[s];
      const float4* p = h4 + (size_t)s * NF4;
      float4 v = p[lane];
      a0.x += v.x * ws; a0.y += v.y * ws; a0.z += v.z * ws; a0.w += v.w * ws;
      if constexpr (NF4 > 64) {
        if (hi) {
          float4 u = p[64 + lane];
          a1.x += u.x * ws; a1.y += u.y * ws; a1.z += u.z * ws; a1.w += u.w * ws;
        }
      }
    }
    float innm = in_norm[n];
    a0.x = (a0.x + c0.x) * innm; a0.y = (a0.y + c0.y) * innm;
    a0.z = (a0.z + c0.z) * innm; a0.w = (a0.w + c0.w) * innm;
    a1.x = (a1.x + c1.x) * innm; a1.y = (a1.y + c1.y) * innm;
    a1.z = (a1.z + c1.z) * innm; a1.w = (a1.w + c1.w) * innm;
    // store to LDS (linear element el -> layout address)
    {
      int el = lane * 4;
      float* dst0;
      if constexpr (IT_LAYOUT) dst0 = &agg[el];
      else { int t = el / F_IN; int i = el - t * F_IN; dst0 = &agg[t * RS + i]; }
      *(float4*)dst0 = a0;
      if constexpr (NF4 > 64) {
        if (hi) {
          int el1 = (64 + lane) * 4;
          float* dst1;
          if constexpr (IT_LAYOUT) dst1 = &agg[el1];
          else { int t = el1 / F_IN; int i = el1 - t * F_IN; dst1 = &agg[t * RS + i]; }
          *(float4*)dst1 = a1;
        }
      }
    }
  }
  __syncthreads();

  if (valid) {
    constexpr int G = F_OUT / 8;  // 5 or 8
    int t = lane >> 3, og = lane & 7;
    float acc[G];
    if constexpr (G == 8) {
      float4 bA = *(const float4*)&bias[og * 8];
      float4 bB = *(const float4*)&bias[og * 8 + 4];
      acc[0] = bA.x; acc[1] = bA.y; acc[2] = bA.z; acc[3] = bA.w;
      acc[4] = bB.x; acc[5] = bB.y; acc[6] = bB.z; acc[7] = bB.w;
    } else {
#pragma unroll
      for (int c = 0; c < G; ++c) acc[c] = bias[og * G + c];
    }
#pragma unroll 4
    for (int i = 0; i < F_IN; ++i) {
      float a;
      if constexpr (IT_LAYOUT) a = agg[i * 8 + t];
      else a = agg[t * RS + i];
      if constexpr (G == 8) {
        float4 wA = *(const float4*)&W[i * F_OUT + og * 8];
        float4 wB = *(const float4*)&W[i * F_OUT + og * 8 + 4];
        acc[0] += a * wA.x; acc[1] += a * wA.y; acc[2] += a * wA.z; acc[3] += a * wA.w;
        acc[4] += a * wB.x; acc[5] += a * wB.y; acc[6] += a * wB.z; acc[7] += a * wB.w;
      } else {
#pragma unroll
        for (int c = 0; c < G; ++c) acc[c] += a * W[i * F_OUT + og * G + c];
      }
    }
    float osc = 1.f;
    if constexpr (SCALE_OUT) osc = out_norm[n];
    float* orow = h_out + (size_t)n * (F_OUT * 8) + t * F_OUT + og * G;
#pragma unroll
    for (int c = 0; c < G; ++c) {
      float v = acc[c];
      if constexpr (RELU) v = fmaxf(v, 0.f);
      acc[c] = v * osc;
    }
    if constexpr (G == 8) {
      *(float4*)&orow[0] = make_float4(acc[0], acc[1], acc[2], acc[3]);
      *(float4*)&orow[4] = make_float4(acc[4], acc[5], acc[6], acc[7]);
    } else {
#pragma unroll
      for (int c = 0; c < G; ++c) orow[c] = acc[c];
    }
  }
}

// ---------------- temporal conv1d (k=3, pad=1) ----------------
// h3 (= d_out, aliasing safe: per-node read->LDS->sync->write) layout [n][t][i];
// out layout [n][o][t]. Wc staged transposed in LDS; one wave per node.
#define CONV_NPW 8
__global__ __launch_bounds__(256) void conv_kernel(const float* h3, const float* __restrict__ Wc,
                                                   const float* __restrict__ bc, float* out, int N) {
  __shared__ float wc_t[192 * 64];      // [(i*3+k)*64 + o], 48 KB
  __shared__ float h3t[4][64 * 12];     // per-wave, [i*12 + t] (pad -> b128-friendly)
  int tid = threadIdx.x, lane = tid & 63, wave = tid >> 6;

  for (int m4 = tid; m4 < 3072; m4 += 256) {  // 12288 floats as float4
    float4 v = ((const float4*)Wc)[m4];
    int m = m4 * 4;
    int o = m / 192, q = m % 192;  // q = i*3+k; float4 never crosses an o row
    wc_t[(q + 0) * 64 + o] = v.x;
    wc_t[(q + 1) * 64 + o] = v.y;
    wc_t[(q + 2) * 64 + o] = v.z;
    wc_t[(q + 3) * 64 + o] = v.w;
  }
  __syncthreads();
  float bo = bc[lane];
  float* ht = h3t[wave];

  for (int it = 0; it < CONV_NPW; ++it) {
    int n = blockIdx.x * (4 * CONV_NPW) + it * 4 + wave;
    bool valid = (n < N);
    if (valid) {
      const float* srcp = &h3[(size_t)n * 512];
#pragma unroll
      for (int r = 0; r < 8; ++r) ht[lane * 12 + r] = srcp[r * 64 + lane];  // transpose
    }
    __syncthreads();
    if (valid) {
      float acc[8];
#pragma unroll
      for (int t = 0; t < 8; ++t) acc[t] = bo;
#pragma unroll 4
      for (int i = 0; i < 64; ++i) {
        float4 hA = *(const float4*)&ht[i * 12];
        float4 hB = *(const float4*)&ht[i * 12 + 4];
        float w0 = wc_t[(i * 3 + 0) * 64 + lane];
        float w1 = wc_t[(i * 3 + 1) * 64 + lane];
        float w2 = wc_t[(i * 3 + 2) * 64 + lane];
        float h[8] = {hA.x, hA.y, hA.z, hA.w, hB.x, hB.y, hB.z, hB.w};
#pragma unroll
        for (int t = 0; t < 8; ++t) acc[t] += w1 * h[t];
#pragma unroll
        for (int t = 1; t < 8; ++t) acc[t] += w0 * h[t - 1];
#pragma unroll
        for (int t = 0; t < 7; ++t) acc[t] += w2 * h[t + 1];
      }
      float4 r0 = make_float4(acc[0], acc[1], acc[2], acc[3]);
      float4 r1 = make_float4(acc[4], acc[5], acc[6], acc[7]);
      float4* dst = (float4*)&out[(size_t)n * 512 + lane * 8];
      dst[0] = r0;
      dst[1] = r1;
    }
    __syncthreads();
  }
}

// ---------------- launch ----------------

extern "C" void kernel_launch(void* const* d_in, const int* in_sizes, int n_in,
                              void* d_out, int out_size, void* d_ws, size_t ws_size,
                              hipStream_t stream) {
  const float* tf = (const float*)d_in[0];
  const int* src = (const int*)d_in[1];
  const int* dst = (const int*)d_in[2];
  const float* W1 = (const float*)d_in[3];
  const float* b1 = (const float*)d_in[4];
  const float* W2 = (const float*)d_in[5];
  const float* b2 = (const float*)d_in[6];
  const float* W3 = (const float*)d_in[7];
  const float* b3 = (const float*)d_in[8];
  const float* Wc = (const float*)d_in[9];
  const float* bc = (const float*)d_in[10];

  int N = in_sizes[0] / 256;  // [N, 32, 8]
  int E = in_sizes[1];

  char* ws = (char*)d_ws;
  size_t pos = 0;
  auto alloc = [&](size_t bytes) -> void* {
    void* p = ws + pos;
    pos += (bytes + 255) & ~(size_t)255;
    return p;
  };
  int* in_deg   = (int*)alloc((size_t)N * 4);
  int* out_deg  = (int*)alloc((size_t)N * 4);
  int* cursor   = (int*)alloc((size_t)N * 4);
  int* in_off   = (int*)alloc((size_t)(N + 1) * 4);
  int* partial  = (int*)alloc((size_t)1024 * 4);
  float* o_norm = (float*)alloc((size_t)N * 4);
  float* i_norm = (float*)alloc((size_t)N * 4);
  int* csr      = (int*)alloc((size_t)E * 4);
  float* h1     = (float*)alloc((size_t)N * 320 * 4);
  float* h2     = (float*)alloc((size_t)N * 512 * 4);
  float* h3     = (float*)d_out;  // reuse d_out as h3 storage (conv is node-local)

  // zero the three atomic counter arrays (contiguous region)
  hipMemsetAsync(in_deg, 0, (size_t)((char*)in_off - (char*)in_deg), stream);

  deg_kernel<<<(E + 255) / 256, 256, 0, stream>>>(src, dst, out_deg, in_deg, E);
  norm_kernel<<<(N + 255) / 256, 256, 0, stream>>>(out_deg, in_deg, o_norm, i_norm, N);

  int P = (N + 1023) / 1024;  // 49 for N=50000; scan_partials handles P<=1024
  scan_partial_kernel<<<P, 256, 0, stream>>>(in_deg, partial, N);
  scan_partials_kernel<<<1, 1024, 0, stream>>>(partial, P);
  scan_apply_kernel<<<P, 1024, 0, stream>>>(in_deg, partial, in_off, N);

  scatter_kernel<<<(E + 255) / 256, 256, 0, stream>>>(src, dst, in_off, cursor, csr, E);

  int lg = (N + 3) / 4;
  // layer1: reads raw tf (needs out_norm in gather), writes h1 pre-scaled by out_norm
  layer_kernel<32, 40, 0, true, true, true, true><<<lg, 256, 0, stream>>>(
      tf, csr, in_off, o_norm, i_norm, W1, b1, h1, N);
  // layer2: h1 already pre-scaled, writes h2 pre-scaled
  layer_kernel<40, 64, 40, false, true, false, true><<<lg, 256, 0, stream>>>(
      h1, csr, in_off, o_norm, i_norm, W2, b2, h2, N);
  // layer3: h2 already pre-scaled, final output unscaled
  layer_kernel<64, 64, 72, false, false, false, false><<<lg, 256, 0, stream>>>(
      h2, csr, in_off, o_norm, i_norm, W3, b3, h3, N);

  conv_kernel<<<(N + 4 * CONV_NPW - 1) / (4 * CONV_NPW), 256, 0, stream>>>(
      h3, Wc, bc, (float*)d_out, N);
}